// Round 1
// baseline (424.641 us; speedup 1.0000x reference)
//
#include <hip/hip_runtime.h>

// softmax(x, axis=-1) * v
// x: [B,H,S,S] fp32, v: [B,H,1,S] fp32, out: [B,H,S,S] fp32
// B=4 H=16 S=1024. One wave (64 lanes) per row of S=1024 floats;
// each lane holds 16 floats (4 x float4) in registers. Row is read once.

#define SEQ 1024
#define F4_PER_ROW (SEQ / 4)   // 256 float4 per row
#define WAVES_PER_BLOCK 4

__global__ __launch_bounds__(256) void softmax_mul_kernel(
    const float* __restrict__ x,
    const float* __restrict__ v,
    float* __restrict__ out,
    int rows) {
  const int wave_in_block = threadIdx.x >> 6;
  const int lane = threadIdx.x & 63;
  const int row = blockIdx.x * WAVES_PER_BLOCK + wave_in_block;
  if (row >= rows) return;

  const size_t row_off = (size_t)row * SEQ;
  const float4* __restrict__ x4 = (const float4*)(x + row_off);
  float4* __restrict__ o4 = (float4*)(out + row_off);
  // v is indexed by (b,h) and the key dim: v_row = row / SEQ (queries share v)
  const float4* __restrict__ v4 = (const float4*)(v + (size_t)(row >> 10) * SEQ);

  // ---- load 16 floats/lane, coalesced: lane i reads float4 #(lane + 64*j)
  float4 d[4];
#pragma unroll
  for (int j = 0; j < 4; ++j) d[j] = x4[lane + 64 * j];

  // ---- row max
  float m = -INFINITY;
#pragma unroll
  for (int j = 0; j < 4; ++j)
    m = fmaxf(m, fmaxf(fmaxf(d[j].x, d[j].y), fmaxf(d[j].z, d[j].w)));
#pragma unroll
  for (int off = 32; off > 0; off >>= 1)
    m = fmaxf(m, __shfl_xor(m, off, 64));

  // ---- exp and row sum
  float s = 0.f;
#pragma unroll
  for (int j = 0; j < 4; ++j) {
    d[j].x = __expf(d[j].x - m);
    d[j].y = __expf(d[j].y - m);
    d[j].z = __expf(d[j].z - m);
    d[j].w = __expf(d[j].w - m);
    s += (d[j].x + d[j].y) + (d[j].z + d[j].w);
  }
#pragma unroll
  for (int off = 32; off > 0; off >>= 1)
    s += __shfl_xor(s, off, 64);

  const float inv = 1.0f / s;

  // ---- scale by v and store
#pragma unroll
  for (int j = 0; j < 4; ++j) {
    const float4 vv = v4[lane + 64 * j];
    float4 o;
    o.x = d[j].x * inv * vv.x;
    o.y = d[j].y * inv * vv.y;
    o.z = d[j].z * inv * vv.z;
    o.w = d[j].w * inv * vv.w;
    o4[lane + 64 * j] = o;
  }
}

extern "C" void kernel_launch(void* const* d_in, const int* in_sizes, int n_in,
                              void* d_out, int out_size, void* d_ws, size_t ws_size,
                              hipStream_t stream) {
  const float* x = (const float*)d_in[0];
  const float* v = (const float*)d_in[1];
  float* out = (float*)d_out;
  const int rows = in_sizes[0] / SEQ;  // B*H*S = 65536
  const int grid = (rows + WAVES_PER_BLOCK - 1) / WAVES_PER_BLOCK;
  softmax_mul_kernel<<<grid, 256, 0, stream>>>(x, v, out, rows);
}

// Round 3
// 415.633 us; speedup vs baseline: 1.0217x; 1.0217x over previous
//
#include <hip/hip_runtime.h>

// out = softmax(x, axis=-1) * v
// x: [B,H,S,S] fp32, v: [B,H,1,S] fp32, out: [B,H,S,S] fp32; B=4 H=16 S=1024.
// One wave per 2 consecutive rows (rows 2w, 2w+1 always share the same (b,h),
// hence the same v slice). Each lane holds 16 floats per row in registers.
// x is streamed once via nontemporal loads; out via nontemporal stores; v
// stays cache-resident (256 KiB total, heavy reuse).

#define SEQ 1024
#define WAVES_PER_BLOCK 4

// native clang vector type — required by __builtin_nontemporal_{load,store}
typedef float vf4 __attribute__((ext_vector_type(4)));

__global__ __launch_bounds__(256) void softmax_mul_kernel(
    const float* __restrict__ x,
    const float* __restrict__ v,
    float* __restrict__ out,
    int npairs) {
  const int wave = threadIdx.x >> 6;
  const int lane = threadIdx.x & 63;
  const int pair = blockIdx.x * WAVES_PER_BLOCK + wave;
  if (pair >= npairs) return;

  const size_t row0 = (size_t)pair * 2;              // even row
  const vf4* __restrict__ x4 = (const vf4*)(x + row0 * SEQ);
  vf4* __restrict__ o4 = (vf4*)(out + row0 * SEQ);
  const vf4* __restrict__ v4 = (const vf4*)(v + (row0 >> 10) * SEQ);

  // ---- issue all global traffic up front: 2 rows of x (nt) + v (cached)
  vf4 a[4], b[4], vv[4];
#pragma unroll
  for (int j = 0; j < 4; ++j) a[j] = __builtin_nontemporal_load(&x4[lane + 64 * j]);
#pragma unroll
  for (int j = 0; j < 4; ++j) b[j] = __builtin_nontemporal_load(&x4[256 + lane + 64 * j]);
#pragma unroll
  for (int j = 0; j < 4; ++j) vv[j] = v4[lane + 64 * j];

  // ---- row maxes (two independent chains, interleaved for ILP)
  float ma = -INFINITY, mb = -INFINITY;
#pragma unroll
  for (int j = 0; j < 4; ++j) {
    ma = fmaxf(ma, fmaxf(fmaxf(a[j].x, a[j].y), fmaxf(a[j].z, a[j].w)));
    mb = fmaxf(mb, fmaxf(fmaxf(b[j].x, b[j].y), fmaxf(b[j].z, b[j].w)));
  }
#pragma unroll
  for (int off = 32; off > 0; off >>= 1) {
    ma = fmaxf(ma, __shfl_xor(ma, off, 64));
    mb = fmaxf(mb, __shfl_xor(mb, off, 64));
  }

  // ---- exp and row sums
  float sa = 0.f, sb = 0.f;
#pragma unroll
  for (int j = 0; j < 4; ++j) {
    a[j].x = __expf(a[j].x - ma); a[j].y = __expf(a[j].y - ma);
    a[j].z = __expf(a[j].z - ma); a[j].w = __expf(a[j].w - ma);
    b[j].x = __expf(b[j].x - mb); b[j].y = __expf(b[j].y - mb);
    b[j].z = __expf(b[j].z - mb); b[j].w = __expf(b[j].w - mb);
    sa += (a[j].x + a[j].y) + (a[j].z + a[j].w);
    sb += (b[j].x + b[j].y) + (b[j].z + b[j].w);
  }
#pragma unroll
  for (int off = 32; off > 0; off >>= 1) {
    sa += __shfl_xor(sa, off, 64);
    sb += __shfl_xor(sb, off, 64);
  }
  const float ia = 1.0f / sa;
  const float ib = 1.0f / sb;

  // ---- scale by v, nontemporal store
#pragma unroll
  for (int j = 0; j < 4; ++j) {
    vf4 oa, ob;
    oa.x = a[j].x * ia * vv[j].x; oa.y = a[j].y * ia * vv[j].y;
    oa.z = a[j].z * ia * vv[j].z; oa.w = a[j].w * ia * vv[j].w;
    ob.x = b[j].x * ib * vv[j].x; ob.y = b[j].y * ib * vv[j].y;
    ob.z = b[j].z * ib * vv[j].z; ob.w = b[j].w * ib * vv[j].w;
    __builtin_nontemporal_store(oa, &o4[lane + 64 * j]);
    __builtin_nontemporal_store(ob, &o4[256 + lane + 64 * j]);
  }
}

extern "C" void kernel_launch(void* const* d_in, const int* in_sizes, int n_in,
                              void* d_out, int out_size, void* d_ws, size_t ws_size,
                              hipStream_t stream) {
  const float* x = (const float*)d_in[0];
  const float* v = (const float*)d_in[1];
  float* out = (float*)d_out;
  const int rows = in_sizes[0] / SEQ;       // B*H*S = 65536
  const int npairs = rows / 2;              // 32768 waves
  const int grid = (npairs + WAVES_PER_BLOCK - 1) / WAVES_PER_BLOCK;
  softmax_mul_kernel<<<grid, 256, 0, stream>>>(x, v, out, npairs);
}